// Round 17
// baseline (221.163 us; speedup 1.0000x reference)
//
#include <hip/hip_runtime.h>
#include <hip/hip_bf16.h>
#include <math.h>

#define D 2048
#define NH 16
#define KHD 8
#define HD 128
#define T_NOISE 1024
#define T_PAD 1024
#define MAX_KV 4096
#define SM_SCALE 0.08838834764831845f  /* 1/sqrt(128) */

typedef __attribute__((ext_vector_type(8))) short short8;
typedef __attribute__((ext_vector_type(4))) short short4v;
typedef __attribute__((ext_vector_type(4))) float f32x4;

__device__ __forceinline__ unsigned short f2bf(float f) {
    union { float f; unsigned u; } v; v.f = f;
    unsigned r = v.u + 0x7fff + ((v.u >> 16) & 1);   // round-nearest-even
    return (unsigned short)(r >> 16);
}
__device__ __forceinline__ float bf2f(short s) {
    union { unsigned u; float f; } v; v.u = ((unsigned)(unsigned short)s) << 16;
    return v.f;
}
__device__ __forceinline__ void gload16(const void* g, void* l) {
    __builtin_amdgcn_global_load_lds(
        (const __attribute__((address_space(1))) unsigned int*)g,
        (__attribute__((address_space(3))) unsigned int*)l, 16, 0, 0);
}
__device__ __forceinline__ unsigned cvtpk(float lo, float hi) {
    unsigned r;
    asm("v_cvt_pk_bf16_f32 %0, %1, %2" : "=v"(r) : "v"(lo), "v"(hi));
    return r;
}

// ---------------------------------------------------------------------------
// Fused prep: cast_concat (blocks 0..2047) + Wk/Wv transpose (2048..3071) +
// Wq transpose (3072..4095). Transposed outputs all have row stride 2048.
// ---------------------------------------------------------------------------
__global__ __launch_bounds__(256)
void prep_all(const float* __restrict__ target_hidden, const float* __restrict__ x_noise,
              short* __restrict__ xbf,
              const float* __restrict__ Wk, const float* __restrict__ Wv,
              const float* __restrict__ Wq,
              short* __restrict__ dK, short* __restrict__ dV, short* __restrict__ dQ) {
    const int bid = blockIdx.x;
    const int tid = threadIdx.x;
    if (bid < 2048) {
        int i = (bid * 256 + tid) * 8;
        const float* src = (i < 1024 * 2048) ? (target_hidden + i)
                                             : (x_noise + (i - 1024 * 2048));
        float4 f0 = *(const float4*)src;
        float4 f1 = *(const float4*)(src + 4);
        short8 s;
        s[0] = (short)f2bf(f0.x); s[1] = (short)f2bf(f0.y);
        s[2] = (short)f2bf(f0.z); s[3] = (short)f2bf(f0.w);
        s[4] = (short)f2bf(f1.x); s[5] = (short)f2bf(f1.y);
        s[6] = (short)f2bf(f1.z); s[7] = (short)f2bf(f1.w);
        *(short8*)(xbf + i) = s;
        return;
    }
    __shared__ short t[64][72];
    const float* W; short* Wt; int r0, c0, C;
    if (bid < 3072) {                       // Wk/Wv: 1024 blocks (16 x 64)
        int j = bid - 2048;
        int bx = j & 15, by = j >> 4;
        const bool isV = by >= 32;
        W = isV ? Wv : Wk; Wt = isV ? dV : dK;
        r0 = (by & 31) * 64; c0 = bx * 64; C = 1024;
    } else {                                // Wq: 1024 blocks (32 x 32)
        int j = bid - 3072;
        int bx = j & 31, by = j >> 5;
        W = Wq; Wt = dQ;
        r0 = by * 64; c0 = bx * 64; C = 2048;
    }
    int rl = tid >> 4, cl4 = (tid & 15) * 4;
    #pragma unroll
    for (int j = 0; j < 4; ++j) {
        int r = rl + j * 16;
        float4 f = *(const float4*)(W + (size_t)(r0 + r) * C + c0 + cl4);
        t[cl4 + 0][r] = (short)f2bf(f.x);
        t[cl4 + 1][r] = (short)f2bf(f.y);
        t[cl4 + 2][r] = (short)f2bf(f.z);
        t[cl4 + 3][r] = (short)f2bf(f.w);
    }
    __syncthreads();
    #pragma unroll
    for (int j = 0; j < 2; ++j) {
        int idx = tid + j * 256;
        int cr = idx >> 3, rc8 = (idx & 7) * 8;
        *(short8*)(Wt + (size_t)(c0 + cr) * 2048 + r0 + rc8) = *(const short8*)&t[cr][rc8];
    }
}

// ---------------------------------------------------------------------------
// Convert + transpose: W f32 [R][C] -> Wt bf16 [C][R]. (Wo only)
// ---------------------------------------------------------------------------
__global__ __launch_bounds__(256)
void conv_transpose(const float* __restrict__ W, short* __restrict__ Wt,
                    int R, int C) {
    __shared__ short t[64][72];
    int tid = threadIdx.x;
    int r0 = blockIdx.y * 64, c0 = blockIdx.x * 64;
    int rl = tid >> 4, cl4 = (tid & 15) * 4;
    #pragma unroll
    for (int j = 0; j < 4; ++j) {
        int r = rl + j * 16;
        float4 f = *(const float4*)(W + (size_t)(r0 + r) * C + c0 + cl4);
        t[cl4 + 0][r] = (short)f2bf(f.x);
        t[cl4 + 1][r] = (short)f2bf(f.y);
        t[cl4 + 2][r] = (short)f2bf(f.z);
        t[cl4 + 3][r] = (short)f2bf(f.w);
    }
    __syncthreads();
    #pragma unroll
    for (int j = 0; j < 2; ++j) {
        int idx = tid + j * 256;
        int cr = idx >> 3, rc8 = (idx & 7) * 8;
        *(short8*)(Wt + (size_t)(c0 + cr) * R + r0 + rc8) = *(const short8*)&t[cr][rc8];
    }
}

// ---------------------------------------------------------------------------
// Fused QKV projection, 64x64 tiles (gemm_o structure + 3-way output split).
// Grid (64, 32): n0 = bx*64 in [0,4096), m0 = by*64. 1536 useful blocks =
// 6 blocks/CU (was 3 at BN=128 — grid-capped occupancy fix).
// ---------------------------------------------------------------------------
__global__ __launch_bounds__(256)
void gemm_qkv64(const short* __restrict__ xbf, const short* __restrict__ Btp,
                short* __restrict__ k_tmpb, short* __restrict__ v_tmpb,
                short* __restrict__ q_tmpb) {
    const int n0 = blockIdx.x * 64;
    const int m0 = blockIdx.y * 64;
    const bool isQ = (n0 >= 2048);
    if (isQ && m0 >= 1024) return;
    const short* A = xbf + (isQ ? (size_t)1024 * 2048 : 0);

    __shared__ __align__(16) short As[64 * 32];
    __shared__ __align__(16) short Bs[64 * 32];
    const int tid = threadIdx.x;
    const int w = tid >> 6, lane = tid & 63;
    const int g = lane >> 4, li = lane & 15;
    const int wr = w >> 1, wc = w & 1;

    f32x4 acc[2][2];
    #pragma unroll
    for (int mi = 0; mi < 2; ++mi)
        #pragma unroll
        for (int ni = 0; ni < 2; ++ni) {
            acc[mi][ni][0] = 0.f; acc[mi][ni][1] = 0.f;
            acc[mi][ni][2] = 0.f; acc[mi][ni][3] = 0.f;
        }

    for (int k0 = 0; k0 < 2048; k0 += 32) {
        int idx = w * 64 + lane;
        int row = idx >> 2, slot = idx & 3;
        gload16(A + (size_t)(m0 + row) * 2048 + k0 + slot * 8,
                (char*)As + (size_t)(w * 64) * 16);
        gload16(Btp + (size_t)(n0 + row) * 2048 + k0 + slot * 8,
                (char*)Bs + (size_t)(w * 64) * 16);
        __syncthreads();
        short8 af[2], bf[2];
        #pragma unroll
        for (int mi = 0; mi < 2; ++mi)
            af[mi] = *(const short8*)&As[(wr * 32 + mi * 16 + li) * 32 + g * 8];
        #pragma unroll
        for (int ni = 0; ni < 2; ++ni)
            bf[ni] = *(const short8*)&Bs[(wc * 32 + ni * 16 + li) * 32 + g * 8];
        #pragma unroll
        for (int mi = 0; mi < 2; ++mi)
            #pragma unroll
            for (int ni = 0; ni < 2; ++ni)
                acc[mi][ni] = __builtin_amdgcn_mfma_f32_16x16x32_bf16(
                    af[mi], bf[ni], acc[mi][ni], 0, 0, 0);
        __syncthreads();
    }
    short* cp; int cbase, ldc2;
    if (n0 < 1024)      { cp = k_tmpb; cbase = 0;    ldc2 = 1024; }
    else if (n0 < 2048) { cp = v_tmpb; cbase = 1024; ldc2 = 1024; }
    else                { cp = q_tmpb; cbase = 2048; ldc2 = 2048; }
    #pragma unroll
    for (int mi = 0; mi < 2; ++mi)
        #pragma unroll
        for (int ni = 0; ni < 2; ++ni) {
            int n = n0 + wc * 32 + ni * 16 + li - cbase;
            #pragma unroll
            for (int r = 0; r < 4; ++r) {
                int m = m0 + wr * 32 + mi * 16 + 4 * g + r;
                cp[(size_t)m * ldc2 + n] = (short)f2bf(acc[mi][ni][r]);
            }
        }
}

// ---------------------------------------------------------------------------
// O-projection GEMM, 64x64 tiles, f32 output. (unchanged)
// ---------------------------------------------------------------------------
__global__ __launch_bounds__(256)
void gemm_o(const short* __restrict__ A, const short* __restrict__ Bt,
            float* __restrict__ C) {
    __shared__ __align__(16) short As[64 * 32];
    __shared__ __align__(16) short Bs[64 * 32];
    const int tid = threadIdx.x;
    const int w = tid >> 6, lane = tid & 63;
    const int g = lane >> 4, li = lane & 15;
    const int wr = w >> 1, wc = w & 1;
    const int m0 = blockIdx.y * 64, n0 = blockIdx.x * 64;

    f32x4 acc[2][2];
    #pragma unroll
    for (int mi = 0; mi < 2; ++mi)
        #pragma unroll
        for (int ni = 0; ni < 2; ++ni) {
            acc[mi][ni][0] = 0.f; acc[mi][ni][1] = 0.f;
            acc[mi][ni][2] = 0.f; acc[mi][ni][3] = 0.f;
        }

    for (int k0 = 0; k0 < 2048; k0 += 32) {
        int idx = w * 64 + lane;
        int row = idx >> 2, slot = idx & 3;
        gload16(A + (size_t)(m0 + row) * 2048 + k0 + slot * 8,
                (char*)As + (size_t)(w * 64) * 16);
        gload16(Bt + (size_t)(n0 + row) * 2048 + k0 + slot * 8,
                (char*)Bs + (size_t)(w * 64) * 16);
        __syncthreads();
        short8 af[2], bf[2];
        #pragma unroll
        for (int mi = 0; mi < 2; ++mi)
            af[mi] = *(const short8*)&As[(wr * 32 + mi * 16 + li) * 32 + g * 8];
        #pragma unroll
        for (int ni = 0; ni < 2; ++ni)
            bf[ni] = *(const short8*)&Bs[(wc * 32 + ni * 16 + li) * 32 + g * 8];
        #pragma unroll
        for (int mi = 0; mi < 2; ++mi)
            #pragma unroll
            for (int ni = 0; ni < 2; ++ni)
                acc[mi][ni] = __builtin_amdgcn_mfma_f32_16x16x32_bf16(
                    af[mi], bf[ni], acc[mi][ni], 0, 0, 0);
        __syncthreads();
    }
    #pragma unroll
    for (int mi = 0; mi < 2; ++mi)
        #pragma unroll
        for (int ni = 0; ni < 2; ++ni) {
            int n = n0 + wc * 32 + ni * 16 + li;
            #pragma unroll
            for (int r = 0; r < 4; ++r) {
                int m = m0 + wr * 32 + mi * 16 + 4 * g + r;
                C[(size_t)m * 2048 + n] = acc[mi][ni][r];
            }
        }
}

// ---------------------------------------------------------------------------
// Wave-parallel fused RMSNorm+RoPE for Q and K in ONE dispatch. (unchanged)
// ---------------------------------------------------------------------------
__global__ __launch_bounds__(256)
void rmsrope_wv(short* __restrict__ qx, short* __restrict__ kx,
                const int* __restrict__ noise_pos, const int* __restrict__ ctx_pos,
                const float* __restrict__ q_scale, const float* __restrict__ k_scale) {
    const int bid = blockIdx.x;
    const bool isK = bid >= 4096;
    const int row = ((isK ? bid - 4096 : bid) << 2) + (threadIdx.x >> 6);
    const int l = threadIdx.x & 63;
    short* x; int hpt, splitT; const int *pA, *pB; const float* scale; float post;
    if (isK) { x = kx; hpt = 8;  pA = ctx_pos;   pB = noise_pos; splitT = 1024; scale = k_scale; post = 1.0f; }
    else     { x = qx; hpt = 16; pA = noise_pos; pB = noise_pos; splitT = 2048; scale = q_scale; post = SM_SCALE; }
    short* xr = x + (size_t)row * HD;
    const float v0 = bf2f(xr[l]), v1 = bf2f(xr[l + 64]);
    float ss = v0 * v0 + v1 * v1;
    #pragma unroll
    for (int off = 1; off < 64; off <<= 1) ss += __shfl_xor(ss, off);
    const float inv = rsqrtf(ss * (1.0f / 128.0f) + 1e-6f);
    const float n0 = v0 * inv * scale[l];
    const float n1 = v1 * inv * scale[l + 64];
    const int t = row / hpt;
    const int pos = (t < splitT) ? pA[t] : pB[t - splitT];
    const float inv_freq = expf((float)l * (-13.815510557964274f / 64.0f));
    const float ang = (float)pos * inv_freq;
    const float c = cosf(ang), s = sinf(ang);
    xr[l]      = (short)f2bf((n0 * c - n1 * s) * post);
    xr[l + 64] = (short)f2bf((n1 * c + n0 * s) * post);
}

// ---------------------------------------------------------------------------
// Cache build. (unchanged from round 16)
// ---------------------------------------------------------------------------
__global__ __launch_bounds__(256)
void cache_scatter2(const float* __restrict__ in_k, const float* __restrict__ in_v,
                    const short* __restrict__ k_tmpb, const short* __restrict__ v_tmpb,
                    float* __restrict__ out_k, float* __restrict__ out_v,
                    short* __restrict__ kbf, short* __restrict__ vbf,
                    const int* __restrict__ clp, const int* __restrict__ acp) {
    const int cache_len = clp[0], actx = acp[0];
    const int noise_start = cache_len + actx;
    const int new_len = noise_start + T_NOISE;
    int i = blockIdx.x * 256 + threadIdx.x;
    int n = i >> 16;
    int rem = i & 65535;
    int pos = rem >> 4;
    int h8 = (rem & 15) << 3;
    size_t co = ((size_t)(n * MAX_KV + pos)) * HD + h8;
    short8 ks8, vs8;
    if (pos >= cache_len && pos < new_len) {
        int tkn = (pos < noise_start) ? (pos - cache_len) : (T_PAD + (pos - noise_start));
        size_t so = ((size_t)(tkn * KHD + (n >> 1))) * HD + h8;
        ks8 = *(const short8*)(k_tmpb + so);
        vs8 = *(const short8*)(v_tmpb + so);
        float4 a, b;
        a.x = bf2f(ks8[0]); a.y = bf2f(ks8[1]); a.z = bf2f(ks8[2]); a.w = bf2f(ks8[3]);
        b.x = bf2f(ks8[4]); b.y = bf2f(ks8[5]); b.z = bf2f(ks8[6]); b.w = bf2f(ks8[7]);
        *(float4*)(out_k + co) = a; *(float4*)(out_k + co + 4) = b;
        a.x = bf2f(vs8[0]); a.y = bf2f(vs8[1]); a.z = bf2f(vs8[2]); a.w = bf2f(vs8[3]);
        b.x = bf2f(vs8[4]); b.y = bf2f(vs8[5]); b.z = bf2f(vs8[6]); b.w = bf2f(vs8[7]);
        *(float4*)(out_v + co) = a; *(float4*)(out_v + co + 4) = b;
    } else {
        float4 ka = *(const float4*)(in_k + co);
        float4 kb = *(const float4*)(in_k + co + 4);
        float4 va = *(const float4*)(in_v + co);
        float4 vb = *(const float4*)(in_v + co + 4);
        *(float4*)(out_k + co) = ka; *(float4*)(out_k + co + 4) = kb;
        *(float4*)(out_v + co) = va; *(float4*)(out_v + co + 4) = vb;
        ks8[0] = (short)f2bf(ka.x); ks8[1] = (short)f2bf(ka.y);
        ks8[2] = (short)f2bf(ka.z); ks8[3] = (short)f2bf(ka.w);
        ks8[4] = (short)f2bf(kb.x); ks8[5] = (short)f2bf(kb.y);
        ks8[6] = (short)f2bf(kb.z); ks8[7] = (short)f2bf(kb.w);
        vs8[0] = (short)f2bf(va.x); vs8[1] = (short)f2bf(va.y);
        vs8[2] = (short)f2bf(va.z); vs8[3] = (short)f2bf(va.w);
        vs8[4] = (short)f2bf(vb.x); vs8[5] = (short)f2bf(vb.y);
        vs8[6] = (short)f2bf(vb.z); vs8[7] = (short)f2bf(vb.w);
    }
    if (pos < new_len) {
        *(short8*)(kbf + co) = ks8;
        *(short8*)(vbf + co) = vs8;
    }
}

// ---------------------------------------------------------------------------
// MFMA bf16 flash attention — round-13 known-good (68 µs, VGPR 124, no
// spill). REQUIRES the (128,2)/256-VGPR budget. (unchanged)
// ---------------------------------------------------------------------------
#define VBUF(b) ((b) * 16896)

__device__ __forceinline__ short4v tr_read(unsigned addr) {
    short4v d;
    asm volatile("ds_read_b64_tr_b16 %0, %1" : "=v"(d) : "v"(addr));
    return d;
}

__global__ __launch_bounds__(128, 2)
void attn_mfma(const short* __restrict__ qbf, const short* __restrict__ kbf,
               const short* __restrict__ vbf, short* __restrict__ opA,
               short* __restrict__ opB, float* __restrict__ mlpart,
               const int* __restrict__ clp, const int* __restrict__ acp) {
    __shared__ __align__(16) char smem[33792];
    const int tid  = threadIdx.x;
    const int w    = tid >> 6;
    const int lane = tid & 63;
    const int g    = lane >> 4;
    const int li   = lane & 15;
    const int bid  = blockIdx.x;
    const int head = 2 * (bid & 7) + ((bid >> 3) & 1);   // XCD-clustered
    const int rest = bid >> 4;
    const int q0   = (rest & 15) * 64;
    const int kvs  = rest >> 4;
    const int new_len = clp[0] + acp[0] + T_NOISE;
    const int ntiles  = (new_len + 63) >> 6;
    const int ntq     = (ntiles + 3) >> 2;

    const short* kb_g = kbf + (size_t)head * MAX_KV * HD;
    const short* vb_g = vbf + (size_t)head * MAX_KV * HD;

    short8 qf[2][4];
    #pragma unroll
    for (int sub = 0; sub < 2; ++sub) {
        const short* qp = qbf + ((size_t)(q0 + w * 32 + sub * 16 + li) * NH + head) * HD;
        #pragma unroll
        for (int ks = 0; ks < 4; ++ks) qf[sub][ks] = *(const short8*)(qp + 32 * ks + 8 * g);
    }

    f32x4 acc[2][8];
    #pragma unroll
    for (int sub = 0; sub < 2; ++sub)
        #pragma unroll
        for (int n = 0; n < 8; ++n) {
            acc[sub][n][0] = 0.f; acc[sub][n][1] = 0.f;
            acc[sub][n][2] = 0.f; acc[sub][n][3] = 0.f;
        }
    float m[2], l[2];
    m[0] = -INFINITY; m[1] = -INFINITY; l[0] = 0.f; l[1] = 0.f;

    const int vrloc = 4 * (lane >> 3) + ((lane >> 1) & 3);
    const int vcof  = (lane & 1) * 8;

    auto STAGE = [&](int tt, int bb) {
        const int base = (kvs * ntq + tt) * 64;
        #pragma unroll
        for (int half = 0; half < 2; ++half)
            #pragma unroll
            for (int i2 = 0; i2 < 4; ++i2) {
                const int ht = w * 4 + i2;
                gload16(vb_g + ((size_t)(base + half * 32 + vrloc) << 7) + ht * 16 + vcof,
                        smem + VBUF(bb) + half * 8448 + ht * 1056);
            }
    };

    short8 kpre[16];
    auto KLOAD = [&](int tt) {
        const int kp0 = (kvs * ntq + tt) << 6;
        const short* kr = kb_g + ((size_t)(kp0 + li) << 7) + g * 8;
        #pragma unroll
        for (int ks = 0; ks < 4; ++ks)
            #pragma unroll
            for (int j = 0; j < 4; ++j)
                kpre[ks * 4 + j] = *(const short8*)(kr + (size_t)(j * 16) * HD + ks * 32);
    };

    auto mkfrag = [&](const float* pA, const float* pB) -> short8 {
        unsigned w0 = cvtpk(pA[0], pA[1]), w1 = cvtpk(pA[2], pA[3]);
        unsigned w2 = cvtpk(pB[0], pB[1]), w3 = cvtpk(pB[2], pB[3]);
        const bool lowg = (g < 2);
        unsigned a0 = lowg ? w2 : w0, a1 = lowg ? w3 : w1;
        unsigned r0 = __shfl_xor((int)a0, 32), r1 = __shfl_xor((int)a1, 32);
        unsigned o0 = lowg ? w0 : w2, o1 = lowg ? w1 : w3;
        const bool sendOwn = (g == 1 || g == 2);
        unsigned b0 = sendOwn ? o0 : r0, b1 = sendOwn ? o1 : r1;
        unsigned g0_ = __shfl_xor((int)b0, 16), g1_ = __shfl_xor((int)b1, 16);
        union { unsigned u[4]; short8 s; } pau;
        pau.u[0] = (g == 0) ? o0 : (g == 2) ? r0 : g0_;
        pau.u[1] = (g == 0) ? o1 : (g == 2) ? r1 : g1_;
        pau.u[2] = (g == 3) ? o0 : (g == 1) ? r0 : g0_;
        pau.u[3] = (g == 3) ? o1 : (g == 1) ? r1 : g1_;
        return pau.s;
    };

    KLOAD(0);
    STAGE(0, 0);
    __syncthreads();

    for (int t = 0; t < ntq; ++t) {
        const int b = t & 1;
        if (t + 1 < ntq) STAGE(t + 1, b ^ 1);
        const int pos0 = (kvs * ntq + t) << 6;
        f32x4 s[4][2];
        #pragma unroll
        for (int j = 0; j < 4; ++j)
            #pragma unroll
            for (int sub = 0; sub < 2; ++sub) {
                s[j][sub][0] = 0.f; s[j][sub][1] = 0.f;
                s[j][sub][2] = 0.f; s[j][sub][3] = 0.f;
            }
        #pragma unroll
        for (int ks = 0; ks < 4; ++ks)
            #pragma unroll
            for (int j = 0; j < 4; ++j) {
                short8 kf = kpre[ks * 4 + j];
                s[j][0] = __builtin_amdgcn_mfma_f32_16x16x32_bf16(kf, qf[0][ks], s[j][0], 0, 0, 0);
                s[j][1] = __builtin_amdgcn_mfma_f32_16x16x32_bf16(kf, qf[1][ks], s[j][1], 0, 0, 0);
            }
        if (t + 1 < ntq) KLOAD(t + 1);
        #pragma unroll
        for (int j = 0; j < 4; ++j)
            #pragma unroll
            for (int r = 0; r < 4; ++r)
                if (pos0 + 16 * j + 4 * g + r >= new_len) {
                    s[j][0][r] = -1e30f; s[j][1][r] = -1e30f;
                }
        short8 pa[2][2];
        #pragma unroll
        for (int sub = 0; sub < 2; ++sub) {
            float tm = -INFINITY;
            #pragma unroll
            for (int j = 0; j < 4; ++j)
                #pragma unroll
                for (int r = 0; r < 4; ++r) tm = fmaxf(tm, s[j][sub][r]);
            tm = fmaxf(tm, __shfl_xor(tm, 16));
            tm = fmaxf(tm, __shfl_xor(tm, 32));
            if (tm > m[sub] + 8.f) {
                const float alpha = __expf(m[sub] - tm);
                m[sub] = tm;
                l[sub] *= alpha;
                #pragma unroll
                for (int n = 0; n < 8; ++n) {
                    acc[sub][n][0] *= alpha; acc[sub][n][1] *= alpha;
                    acc[sub][n][2] *= alpha; acc[sub][n][3] *= alpha;
                }
            }
            const float mb = m[sub];
            float p[4][4];
            float rs = 0.f;
            #pragma unroll
            for (int j = 0; j < 4; ++j)
                #pragma unroll
                for (int r = 0; r < 4; ++r) {
                    p[j][r] = __expf(s[j][sub][r] - mb);
                    rs += p[j][r];
                }
            rs += __shfl_xor(rs, 16);
            rs += __shfl_xor(rs, 32);
            l[sub] += rs;
            pa[sub][0] = mkfrag(p[0], p[1]);
            pa[sub][1] = mkfrag(p[2], p[3]);
        }
        #pragma unroll
        for (int half = 0; half < 2; ++half) {
            const unsigned vb0 = (unsigned)(size_t)(smem + VBUF(b)) + half * 8448
                               + g * 256 + li * 8;
            short4v vt[16];
            #pragma unroll
            for (int h2 = 0; h2 < 8; ++h2) {
                vt[2 * h2]     = tr_read(vb0 + h2 * 1056);
                vt[2 * h2 + 1] = tr_read(vb0 + h2 * 1056 + 128);
            }
            asm volatile("s_waitcnt lgkmcnt(0)" ::: "memory");
            __builtin_amdgcn_sched_barrier(0);
            #pragma unroll
            for (int h2 = 0; h2 < 8; ++h2) {
                short8 vf = __builtin_shufflevector(vt[2 * h2], vt[2 * h2 + 1],
                                                    0, 1, 2, 3, 4, 5, 6, 7);
                acc[0][h2] = __builtin_amdgcn_mfma_f32_16x16x32_bf16(vf, pa[0][half], acc[0][h2], 0, 0, 0);
                acc[1][h2] = __builtin_amdgcn_mfma_f32_16x16x32_bf16(vf, pa[1][half], acc[1][h2], 0, 0, 0);
            }
        }
        __syncthreads();
    }

    short* op = (kvs < 2) ? (opA + (size_t)kvs * 16 * 1024 * 128)
                          : (opB + (size_t)(kvs - 2) * 16 * 1024 * 128);
    #pragma unroll
    for (int sub = 0; sub < 2; ++sub) {
        const int qrow = q0 + w * 32 + sub * 16 + li;
        const size_t ro = ((size_t)(head << 10) + qrow) * 128;
        #pragma unroll
        for (int n = 0; n < 8; ++n) {
            short4v o4;
            o4[0] = (short)f2bf(acc[sub][n][0]); o4[1] = (short)f2bf(acc[sub][n][1]);
            o4[2] = (short)f2bf(acc[sub][n][2]); o4[3] = (short)f2bf(acc[sub][n][3]);
            *(short4v*)(op + ro + 16 * n + 4 * g) = o4;
        }
        if (g == 0) {
            float* ml = mlpart + (((size_t)(kvs * 16 + head) << 10) + qrow) * 2;
            ml[0] = m[sub]; ml[1] = l[sub];
        }
    }
}

// ---------------------------------------------------------------------------
// Merge the 4 KV-split partials -> a_bf. (unchanged)
// ---------------------------------------------------------------------------
__global__ __launch_bounds__(256)
void attn_merge(const short* __restrict__ opA, const short* __restrict__ opB,
                const float* __restrict__ mlpart, short* __restrict__ a_bf) {
    int gid = blockIdx.x * 256 + threadIdx.x;
    int row = gid >> 4;
    int c8  = (gid & 15) * 8;
    int head = row >> 10, q = row & 1023;
    float mg[4], lg[4], mstar = -INFINITY;
    #pragma unroll
    for (int s = 0; s < 4; ++s) {
        const float* ml = mlpart + (((size_t)(s * 16 + head) << 10) + q) * 2;
        mg[s] = ml[0]; lg[s] = ml[1];
        mstar = fmaxf(mstar, mg[s]);
    }
    float cg[4], lstar = 0.f;
    #pragma unroll
    for (int s = 0; s < 4; ++s) { cg[s] = __expf(mg[s] - mstar); lstar += lg[s] * cg[s]; }
    const float inv = 1.0f / lstar;
    float o[8] = {};
    #pragma unroll
    for (int s = 0; s < 4; ++s) {
        const short* op = (s < 2) ? (opA + (size_t)s * 16 * 1024 * 128)
                                  : (opB + (size_t)(s - 2) * 16 * 1024 * 128);
        short8 v = *(const short8*)(op + (((size_t)(head << 10)) + q) * 128 + c8);
        #pragma unroll
        for (int j = 0; j < 8; ++j) o[j] += cg[s] * bf2f(v[j]);
    }
    short8 o8;
    #pragma unroll
    for (int j = 0; j < 8; ++j) o8[j] = (short)f2bf(o[j] * inv);
    *(short8*)(a_bf + (size_t)q * 2048 + head * 128 + c8) = o8;
}

// ---------------------------------------------------------------------------
extern "C" void kernel_launch(void* const* d_in, const int* in_sizes, int n_in,
                              void* d_out, int out_size, void* d_ws, size_t ws_size,
                              hipStream_t stream) {
    const float* x_noise       = (const float*)d_in[0];
    const float* target_hidden = (const float*)d_in[1];
    const int*   noise_pos     = (const int*)d_in[2];
    const int*   ctx_pos       = (const int*)d_in[3];
    const float* in_k          = (const float*)d_in[4];
    const float* in_v          = (const float*)d_in[5];
    const int*   clp           = (const int*)d_in[6];
    const int*   acp           = (const int*)d_in[7];
    const float* Wq            = (const float*)d_in[8];
    const float* Wk            = (const float*)d_in[9];
    const float* Wv            = (const float*)d_in[10];
    const float* Wo            = (const float*)d_in[11];
    const float* q_scale       = (const float*)d_in[12];
    const float* k_scale       = (const float*)d_in[13];

    float* out   = (float*)d_out;
    float* out_k = out + (size_t)T_NOISE * D;
    float* out_v = out_k + (size_t)NH * MAX_KV * HD;

    float* ws     = (float*)d_ws;
    const size_t M1 = 1024u * 1024u;
    short* q_tmpb = (short*)ws;                   // [0,1M) fl
    short* a_bf   = q_tmpb;                       // overlay (q dead after attn)
    short* k_tmpb = (short*)(ws + 1 * M1);        // [1M,2M)
    short* v_tmpb = (short*)(ws + 2 * M1);        // [2M,3M)
    float* mlpart = (float*)v_tmpb;               // overlay (v_tmpb dead after scatter)
    short* xbf    = (short*)(ws + 3 * M1);        // [3M,5M)
    short* opartA = xbf;                          // overlay (xbf dead after gemm_qkv)
    short* btpack = (short*)(ws + 5 * M1);        // [5M,9M)
    short* wo_t   = btpack;                       // overlay rows 0..2047 post-QKV
    short* opartB = (short*)(ws + 7 * M1);        // overlay btpack Wq rows (dead)
    short* kbf    = (short*)(ws + 9 * M1);        // [9M,13M)
    short* vbf    = (short*)(ws + 13 * M1);       // [13M,17M)

    dim3 blk(256);
    prep_all<<<4096, blk, 0, stream>>>(target_hidden, x_noise, xbf,
                                       Wk, Wv, Wq,
                                       btpack, btpack + (size_t)1024 * 2048,
                                       btpack + (size_t)2048 * 2048);
    gemm_qkv64<<<dim3(64, 32), blk, 0, stream>>>(xbf, btpack, k_tmpb, v_tmpb, q_tmpb);
    conv_transpose<<<dim3(32, 32), blk, 0, stream>>>(Wo, wo_t, 2048, 2048);
    rmsrope_wv<<<8192, blk, 0, stream>>>(q_tmpb, k_tmpb, noise_pos, ctx_pos,
                                         q_scale, k_scale);
    cache_scatter2<<<4096, blk, 0, stream>>>(in_k, in_v, k_tmpb, v_tmpb,
                                             out_k, out_v, kbf, vbf, clp, acp);
    attn_mfma<<<1024, 128, 0, stream>>>(q_tmpb, kbf, vbf, opartA, opartB, mlpart, clp, acp);
    attn_merge<<<1024, blk, 0, stream>>>(opartA, opartB, mlpart, a_bf);
    gemm_o<<<dim3(32, 16), blk, 0, stream>>>(a_bf, wo_t, out);
}

// Round 18
// 197.082 us; speedup vs baseline: 1.1222x; 1.1222x over previous
//
#include <hip/hip_runtime.h>
#include <hip/hip_bf16.h>
#include <math.h>

#define D 2048
#define NH 16
#define KHD 8
#define HD 128
#define T_NOISE 1024
#define T_PAD 1024
#define MAX_KV 4096
#define SM_SCALE 0.08838834764831845f  /* 1/sqrt(128) */

typedef __attribute__((ext_vector_type(8))) short short8;
typedef __attribute__((ext_vector_type(4))) short short4v;
typedef __attribute__((ext_vector_type(4))) float f32x4;

__device__ __forceinline__ unsigned short f2bf(float f) {
    union { float f; unsigned u; } v; v.f = f;
    unsigned r = v.u + 0x7fff + ((v.u >> 16) & 1);   // round-nearest-even
    return (unsigned short)(r >> 16);
}
__device__ __forceinline__ float bf2f(short s) {
    union { unsigned u; float f; } v; v.u = ((unsigned)(unsigned short)s) << 16;
    return v.f;
}
__device__ __forceinline__ void gload16(const void* g, void* l) {
    __builtin_amdgcn_global_load_lds(
        (const __attribute__((address_space(1))) unsigned int*)g,
        (__attribute__((address_space(3))) unsigned int*)l, 16, 0, 0);
}
__device__ __forceinline__ unsigned cvtpk(float lo, float hi) {
    unsigned r;
    asm("v_cvt_pk_bf16_f32 %0, %1, %2" : "=v"(r) : "v"(lo), "v"(hi));
    return r;
}

// ---------------------------------------------------------------------------
// Fused prep: cast_concat (blocks 0..2047) + Wk/Wv transpose (2048..3071) +
// Wq transpose (3072..4095). (unchanged from round 17 — not implicated)
// ---------------------------------------------------------------------------
__global__ __launch_bounds__(256)
void prep_all(const float* __restrict__ target_hidden, const float* __restrict__ x_noise,
              short* __restrict__ xbf,
              const float* __restrict__ Wk, const float* __restrict__ Wv,
              const float* __restrict__ Wq,
              short* __restrict__ dK, short* __restrict__ dV, short* __restrict__ dQ) {
    const int bid = blockIdx.x;
    const int tid = threadIdx.x;
    if (bid < 2048) {
        int i = (bid * 256 + tid) * 8;
        const float* src = (i < 1024 * 2048) ? (target_hidden + i)
                                             : (x_noise + (i - 1024 * 2048));
        float4 f0 = *(const float4*)src;
        float4 f1 = *(const float4*)(src + 4);
        short8 s;
        s[0] = (short)f2bf(f0.x); s[1] = (short)f2bf(f0.y);
        s[2] = (short)f2bf(f0.z); s[3] = (short)f2bf(f0.w);
        s[4] = (short)f2bf(f1.x); s[5] = (short)f2bf(f1.y);
        s[6] = (short)f2bf(f1.z); s[7] = (short)f2bf(f1.w);
        *(short8*)(xbf + i) = s;
        return;
    }
    __shared__ short t[64][72];
    const float* W; short* Wt; int r0, c0, C;
    if (bid < 3072) {                       // Wk/Wv: 1024 blocks (16 x 64)
        int j = bid - 2048;
        int bx = j & 15, by = j >> 4;
        const bool isV = by >= 32;
        W = isV ? Wv : Wk; Wt = isV ? dV : dK;
        r0 = (by & 31) * 64; c0 = bx * 64; C = 1024;
    } else {                                // Wq: 1024 blocks (32 x 32)
        int j = bid - 3072;
        int bx = j & 31, by = j >> 5;
        W = Wq; Wt = dQ;
        r0 = by * 64; c0 = bx * 64; C = 2048;
    }
    int rl = tid >> 4, cl4 = (tid & 15) * 4;
    #pragma unroll
    for (int j = 0; j < 4; ++j) {
        int r = rl + j * 16;
        float4 f = *(const float4*)(W + (size_t)(r0 + r) * C + c0 + cl4);
        t[cl4 + 0][r] = (short)f2bf(f.x);
        t[cl4 + 1][r] = (short)f2bf(f.y);
        t[cl4 + 2][r] = (short)f2bf(f.z);
        t[cl4 + 3][r] = (short)f2bf(f.w);
    }
    __syncthreads();
    #pragma unroll
    for (int j = 0; j < 2; ++j) {
        int idx = tid + j * 256;
        int cr = idx >> 3, rc8 = (idx & 7) * 8;
        *(short8*)(Wt + (size_t)(c0 + cr) * 2048 + r0 + rc8) = *(const short8*)&t[cr][rc8];
    }
}

// ---------------------------------------------------------------------------
// Convert + transpose: W f32 [R][C] -> Wt bf16 [C][R]. (Wo only)
// ---------------------------------------------------------------------------
__global__ __launch_bounds__(256)
void conv_transpose(const float* __restrict__ W, short* __restrict__ Wt,
                    int R, int C) {
    __shared__ short t[64][72];
    int tid = threadIdx.x;
    int r0 = blockIdx.y * 64, c0 = blockIdx.x * 64;
    int rl = tid >> 4, cl4 = (tid & 15) * 4;
    #pragma unroll
    for (int j = 0; j < 4; ++j) {
        int r = rl + j * 16;
        float4 f = *(const float4*)(W + (size_t)(r0 + r) * C + c0 + cl4);
        t[cl4 + 0][r] = (short)f2bf(f.x);
        t[cl4 + 1][r] = (short)f2bf(f.y);
        t[cl4 + 2][r] = (short)f2bf(f.z);
        t[cl4 + 3][r] = (short)f2bf(f.w);
    }
    __syncthreads();
    #pragma unroll
    for (int j = 0; j < 2; ++j) {
        int idx = tid + j * 256;
        int cr = idx >> 3, rc8 = (idx & 7) * 8;
        *(short8*)(Wt + (size_t)(c0 + cr) * R + r0 + rc8) = *(const short8*)&t[cr][rc8];
    }
}

// ---------------------------------------------------------------------------
// Fused QKV projection, BM=64 / BN=128 tiles — ROUND-16 KNOWN-GOOD REVERT.
// Round-17's 64x64 retile doubled B-panel fetch (52 MB/dispatch, 81 µs) —
// panel reuse beats occupancy for this GEMM. Grid (32, 32).
// ---------------------------------------------------------------------------
__global__ __launch_bounds__(256)
void gemm_qkv64(const short* __restrict__ xbf, const short* __restrict__ Btp,
                short* __restrict__ k_tmpb, short* __restrict__ v_tmpb,
                short* __restrict__ q_tmpb) {
    const int n0 = blockIdx.x * 128;
    const int m0 = blockIdx.y * 64;
    const bool isQ = (n0 >= 2048);
    if (isQ && m0 >= 1024) return;
    const short* A = xbf + (isQ ? (size_t)1024 * 2048 : 0);

    __shared__ __align__(16) short As[64 * 32];
    __shared__ __align__(16) short Bs[128 * 32];
    const int tid = threadIdx.x;
    const int w = tid >> 6, lane = tid & 63;
    const int g = lane >> 4, li = lane & 15;
    const int wr = w >> 1, wc = w & 1;

    f32x4 acc[2][4];
    #pragma unroll
    for (int mi = 0; mi < 2; ++mi)
        #pragma unroll
        for (int ni = 0; ni < 4; ++ni) {
            acc[mi][ni][0] = 0.f; acc[mi][ni][1] = 0.f;
            acc[mi][ni][2] = 0.f; acc[mi][ni][3] = 0.f;
        }

    for (int k0 = 0; k0 < 2048; k0 += 32) {
        {
            int idx = w * 64 + lane;
            int row = idx >> 2, slot = idx & 3;
            gload16(A + (size_t)(m0 + row) * 2048 + k0 + slot * 8,
                    (char*)As + (size_t)(w * 64) * 16);
        }
        #pragma unroll
        for (int i = 0; i < 2; ++i) {
            int idx = i * 256 + w * 64 + lane;
            int row = idx >> 2, slot = idx & 3;
            gload16(Btp + (size_t)(n0 + row) * 2048 + k0 + slot * 8,
                    (char*)Bs + (size_t)(i * 256 + w * 64) * 16);
        }
        __syncthreads();
        short8 af[2], bf[4];
        #pragma unroll
        for (int mi = 0; mi < 2; ++mi)
            af[mi] = *(const short8*)&As[(wr * 32 + mi * 16 + li) * 32 + g * 8];
        #pragma unroll
        for (int ni = 0; ni < 4; ++ni)
            bf[ni] = *(const short8*)&Bs[(wc * 64 + ni * 16 + li) * 32 + g * 8];
        #pragma unroll
        for (int mi = 0; mi < 2; ++mi)
            #pragma unroll
            for (int ni = 0; ni < 4; ++ni)
                acc[mi][ni] = __builtin_amdgcn_mfma_f32_16x16x32_bf16(
                    af[mi], bf[ni], acc[mi][ni], 0, 0, 0);
        __syncthreads();
    }
    short* cp; int cbase, ldc2;
    if (n0 < 1024)      { cp = k_tmpb; cbase = 0;    ldc2 = 1024; }
    else if (n0 < 2048) { cp = v_tmpb; cbase = 1024; ldc2 = 1024; }
    else                { cp = q_tmpb; cbase = 2048; ldc2 = 2048; }
    #pragma unroll
    for (int mi = 0; mi < 2; ++mi)
        #pragma unroll
        for (int ni = 0; ni < 4; ++ni) {
            int n = n0 + wc * 64 + ni * 16 + li - cbase;
            #pragma unroll
            for (int r = 0; r < 4; ++r) {
                int m = m0 + wr * 32 + mi * 16 + 4 * g + r;
                cp[(size_t)m * ldc2 + n] = (short)f2bf(acc[mi][ni][r]);
            }
        }
}

// ---------------------------------------------------------------------------
// O-projection GEMM, 64x64 tiles, f32 output. (unchanged)
// ---------------------------------------------------------------------------
__global__ __launch_bounds__(256)
void gemm_o(const short* __restrict__ A, const short* __restrict__ Bt,
            float* __restrict__ C) {
    __shared__ __align__(16) short As[64 * 32];
    __shared__ __align__(16) short Bs[64 * 32];
    const int tid = threadIdx.x;
    const int w = tid >> 6, lane = tid & 63;
    const int g = lane >> 4, li = lane & 15;
    const int wr = w >> 1, wc = w & 1;
    const int m0 = blockIdx.y * 64, n0 = blockIdx.x * 64;

    f32x4 acc[2][2];
    #pragma unroll
    for (int mi = 0; mi < 2; ++mi)
        #pragma unroll
        for (int ni = 0; ni < 2; ++ni) {
            acc[mi][ni][0] = 0.f; acc[mi][ni][1] = 0.f;
            acc[mi][ni][2] = 0.f; acc[mi][ni][3] = 0.f;
        }

    for (int k0 = 0; k0 < 2048; k0 += 32) {
        int idx = w * 64 + lane;
        int row = idx >> 2, slot = idx & 3;
        gload16(A + (size_t)(m0 + row) * 2048 + k0 + slot * 8,
                (char*)As + (size_t)(w * 64) * 16);
        gload16(Bt + (size_t)(n0 + row) * 2048 + k0 + slot * 8,
                (char*)Bs + (size_t)(w * 64) * 16);
        __syncthreads();
        short8 af[2], bf[2];
        #pragma unroll
        for (int mi = 0; mi < 2; ++mi)
            af[mi] = *(const short8*)&As[(wr * 32 + mi * 16 + li) * 32 + g * 8];
        #pragma unroll
        for (int ni = 0; ni < 2; ++ni)
            bf[ni] = *(const short8*)&Bs[(wc * 32 + ni * 16 + li) * 32 + g * 8];
        #pragma unroll
        for (int mi = 0; mi < 2; ++mi)
            #pragma unroll
            for (int ni = 0; ni < 2; ++ni)
                acc[mi][ni] = __builtin_amdgcn_mfma_f32_16x16x32_bf16(
                    af[mi], bf[ni], acc[mi][ni], 0, 0, 0);
        __syncthreads();
    }
    #pragma unroll
    for (int mi = 0; mi < 2; ++mi)
        #pragma unroll
        for (int ni = 0; ni < 2; ++ni) {
            int n = n0 + wc * 32 + ni * 16 + li;
            #pragma unroll
            for (int r = 0; r < 4; ++r) {
                int m = m0 + wr * 32 + mi * 16 + 4 * g + r;
                C[(size_t)m * 2048 + n] = acc[mi][ni][r];
            }
        }
}

// ---------------------------------------------------------------------------
// Wave-parallel fused RMSNorm+RoPE for Q and K in ONE dispatch. (unchanged)
// ---------------------------------------------------------------------------
__global__ __launch_bounds__(256)
void rmsrope_wv(short* __restrict__ qx, short* __restrict__ kx,
                const int* __restrict__ noise_pos, const int* __restrict__ ctx_pos,
                const float* __restrict__ q_scale, const float* __restrict__ k_scale) {
    const int bid = blockIdx.x;
    const bool isK = bid >= 4096;
    const int row = ((isK ? bid - 4096 : bid) << 2) + (threadIdx.x >> 6);
    const int l = threadIdx.x & 63;
    short* x; int hpt, splitT; const int *pA, *pB; const float* scale; float post;
    if (isK) { x = kx; hpt = 8;  pA = ctx_pos;   pB = noise_pos; splitT = 1024; scale = k_scale; post = 1.0f; }
    else     { x = qx; hpt = 16; pA = noise_pos; pB = noise_pos; splitT = 2048; scale = q_scale; post = SM_SCALE; }
    short* xr = x + (size_t)row * HD;
    const float v0 = bf2f(xr[l]), v1 = bf2f(xr[l + 64]);
    float ss = v0 * v0 + v1 * v1;
    #pragma unroll
    for (int off = 1; off < 64; off <<= 1) ss += __shfl_xor(ss, off);
    const float inv = rsqrtf(ss * (1.0f / 128.0f) + 1e-6f);
    const float n0 = v0 * inv * scale[l];
    const float n1 = v1 * inv * scale[l + 64];
    const int t = row / hpt;
    const int pos = (t < splitT) ? pA[t] : pB[t - splitT];
    const float inv_freq = expf((float)l * (-13.815510557964274f / 64.0f));
    const float ang = (float)pos * inv_freq;
    const float c = cosf(ang), s = sinf(ang);
    xr[l]      = (short)f2bf((n0 * c - n1 * s) * post);
    xr[l + 64] = (short)f2bf((n1 * c + n0 * s) * post);
}

// ---------------------------------------------------------------------------
// Cache build. (unchanged)
// ---------------------------------------------------------------------------
__global__ __launch_bounds__(256)
void cache_scatter2(const float* __restrict__ in_k, const float* __restrict__ in_v,
                    const short* __restrict__ k_tmpb, const short* __restrict__ v_tmpb,
                    float* __restrict__ out_k, float* __restrict__ out_v,
                    short* __restrict__ kbf, short* __restrict__ vbf,
                    const int* __restrict__ clp, const int* __restrict__ acp) {
    const int cache_len = clp[0], actx = acp[0];
    const int noise_start = cache_len + actx;
    const int new_len = noise_start + T_NOISE;
    int i = blockIdx.x * 256 + threadIdx.x;
    int n = i >> 16;
    int rem = i & 65535;
    int pos = rem >> 4;
    int h8 = (rem & 15) << 3;
    size_t co = ((size_t)(n * MAX_KV + pos)) * HD + h8;
    short8 ks8, vs8;
    if (pos >= cache_len && pos < new_len) {
        int tkn = (pos < noise_start) ? (pos - cache_len) : (T_PAD + (pos - noise_start));
        size_t so = ((size_t)(tkn * KHD + (n >> 1))) * HD + h8;
        ks8 = *(const short8*)(k_tmpb + so);
        vs8 = *(const short8*)(v_tmpb + so);
        float4 a, b;
        a.x = bf2f(ks8[0]); a.y = bf2f(ks8[1]); a.z = bf2f(ks8[2]); a.w = bf2f(ks8[3]);
        b.x = bf2f(ks8[4]); b.y = bf2f(ks8[5]); b.z = bf2f(ks8[6]); b.w = bf2f(ks8[7]);
        *(float4*)(out_k + co) = a; *(float4*)(out_k + co + 4) = b;
        a.x = bf2f(vs8[0]); a.y = bf2f(vs8[1]); a.z = bf2f(vs8[2]); a.w = bf2f(vs8[3]);
        b.x = bf2f(vs8[4]); b.y = bf2f(vs8[5]); b.z = bf2f(vs8[6]); b.w = bf2f(vs8[7]);
        *(float4*)(out_v + co) = a; *(float4*)(out_v + co + 4) = b;
    } else {
        float4 ka = *(const float4*)(in_k + co);
        float4 kb = *(const float4*)(in_k + co + 4);
        float4 va = *(const float4*)(in_v + co);
        float4 vb = *(const float4*)(in_v + co + 4);
        *(float4*)(out_k + co) = ka; *(float4*)(out_k + co + 4) = kb;
        *(float4*)(out_v + co) = va; *(float4*)(out_v + co + 4) = vb;
        ks8[0] = (short)f2bf(ka.x); ks8[1] = (short)f2bf(ka.y);
        ks8[2] = (short)f2bf(ka.z); ks8[3] = (short)f2bf(ka.w);
        ks8[4] = (short)f2bf(kb.x); ks8[5] = (short)f2bf(kb.y);
        ks8[6] = (short)f2bf(kb.z); ks8[7] = (short)f2bf(kb.w);
        vs8[0] = (short)f2bf(va.x); vs8[1] = (short)f2bf(va.y);
        vs8[2] = (short)f2bf(va.z); vs8[3] = (short)f2bf(va.w);
        vs8[4] = (short)f2bf(vb.x); vs8[5] = (short)f2bf(vb.y);
        vs8[6] = (short)f2bf(vb.z); vs8[7] = (short)f2bf(vb.w);
    }
    if (pos < new_len) {
        *(short8*)(kbf + co) = ks8;
        *(short8*)(vbf + co) = vs8;
    }
}

// ---------------------------------------------------------------------------
// MFMA bf16 flash attention — round-13 known-good (68 µs, VGPR 124, no
// spill). REQUIRES the (128,2)/256-VGPR budget. (unchanged)
// ---------------------------------------------------------------------------
#define VBUF(b) ((b) * 16896)

__device__ __forceinline__ short4v tr_read(unsigned addr) {
    short4v d;
    asm volatile("ds_read_b64_tr_b16 %0, %1" : "=v"(d) : "v"(addr));
    return d;
}

__global__ __launch_bounds__(128, 2)
void attn_mfma(const short* __restrict__ qbf, const short* __restrict__ kbf,
               const short* __restrict__ vbf, short* __restrict__ opA,
               short* __restrict__ opB, float* __restrict__ mlpart,
               const int* __restrict__ clp, const int* __restrict__ acp) {
    __shared__ __align__(16) char smem[33792];
    const int tid  = threadIdx.x;
    const int w    = tid >> 6;
    const int lane = tid & 63;
    const int g    = lane >> 4;
    const int li   = lane & 15;
    const int bid  = blockIdx.x;
    const int head = 2 * (bid & 7) + ((bid >> 3) & 1);   // XCD-clustered
    const int rest = bid >> 4;
    const int q0   = (rest & 15) * 64;
    const int kvs  = rest >> 4;
    const int new_len = clp[0] + acp[0] + T_NOISE;
    const int ntiles  = (new_len + 63) >> 6;
    const int ntq     = (ntiles + 3) >> 2;

    const short* kb_g = kbf + (size_t)head * MAX_KV * HD;
    const short* vb_g = vbf + (size_t)head * MAX_KV * HD;

    short8 qf[2][4];
    #pragma unroll
    for (int sub = 0; sub < 2; ++sub) {
        const short* qp = qbf + ((size_t)(q0 + w * 32 + sub * 16 + li) * NH + head) * HD;
        #pragma unroll
        for (int ks = 0; ks < 4; ++ks) qf[sub][ks] = *(const short8*)(qp + 32 * ks + 8 * g);
    }

    f32x4 acc[2][8];
    #pragma unroll
    for (int sub = 0; sub < 2; ++sub)
        #pragma unroll
        for (int n = 0; n < 8; ++n) {
            acc[sub][n][0] = 0.f; acc[sub][n][1] = 0.f;
            acc[sub][n][2] = 0.f; acc[sub][n][3] = 0.f;
        }
    float m[2], l[2];
    m[0] = -INFINITY; m[1] = -INFINITY; l[0] = 0.f; l[1] = 0.f;

    const int vrloc = 4 * (lane >> 3) + ((lane >> 1) & 3);
    const int vcof  = (lane & 1) * 8;

    auto STAGE = [&](int tt, int bb) {
        const int base = (kvs * ntq + tt) * 64;
        #pragma unroll
        for (int half = 0; half < 2; ++half)
            #pragma unroll
            for (int i2 = 0; i2 < 4; ++i2) {
                const int ht = w * 4 + i2;
                gload16(vb_g + ((size_t)(base + half * 32 + vrloc) << 7) + ht * 16 + vcof,
                        smem + VBUF(bb) + half * 8448 + ht * 1056);
            }
    };

    short8 kpre[16];
    auto KLOAD = [&](int tt) {
        const int kp0 = (kvs * ntq + tt) << 6;
        const short* kr = kb_g + ((size_t)(kp0 + li) << 7) + g * 8;
        #pragma unroll
        for (int ks = 0; ks < 4; ++ks)
            #pragma unroll
            for (int j = 0; j < 4; ++j)
                kpre[ks * 4 + j] = *(const short8*)(kr + (size_t)(j * 16) * HD + ks * 32);
    };

    auto mkfrag = [&](const float* pA, const float* pB) -> short8 {
        unsigned w0 = cvtpk(pA[0], pA[1]), w1 = cvtpk(pA[2], pA[3]);
        unsigned w2 = cvtpk(pB[0], pB[1]), w3 = cvtpk(pB[2], pB[3]);
        const bool lowg = (g < 2);
        unsigned a0 = lowg ? w2 : w0, a1 = lowg ? w3 : w1;
        unsigned r0 = __shfl_xor((int)a0, 32), r1 = __shfl_xor((int)a1, 32);
        unsigned o0 = lowg ? w0 : w2, o1 = lowg ? w1 : w3;
        const bool sendOwn = (g == 1 || g == 2);
        unsigned b0 = sendOwn ? o0 : r0, b1 = sendOwn ? o1 : r1;
        unsigned g0_ = __shfl_xor((int)b0, 16), g1_ = __shfl_xor((int)b1, 16);
        union { unsigned u[4]; short8 s; } pau;
        pau.u[0] = (g == 0) ? o0 : (g == 2) ? r0 : g0_;
        pau.u[1] = (g == 0) ? o1 : (g == 2) ? r1 : g1_;
        pau.u[2] = (g == 3) ? o0 : (g == 1) ? r0 : g0_;
        pau.u[3] = (g == 3) ? o1 : (g == 1) ? r1 : g1_;
        return pau.s;
    };

    KLOAD(0);
    STAGE(0, 0);
    __syncthreads();

    for (int t = 0; t < ntq; ++t) {
        const int b = t & 1;
        if (t + 1 < ntq) STAGE(t + 1, b ^ 1);
        const int pos0 = (kvs * ntq + t) << 6;
        f32x4 s[4][2];
        #pragma unroll
        for (int j = 0; j < 4; ++j)
            #pragma unroll
            for (int sub = 0; sub < 2; ++sub) {
                s[j][sub][0] = 0.f; s[j][sub][1] = 0.f;
                s[j][sub][2] = 0.f; s[j][sub][3] = 0.f;
            }
        #pragma unroll
        for (int ks = 0; ks < 4; ++ks)
            #pragma unroll
            for (int j = 0; j < 4; ++j) {
                short8 kf = kpre[ks * 4 + j];
                s[j][0] = __builtin_amdgcn_mfma_f32_16x16x32_bf16(kf, qf[0][ks], s[j][0], 0, 0, 0);
                s[j][1] = __builtin_amdgcn_mfma_f32_16x16x32_bf16(kf, qf[1][ks], s[j][1], 0, 0, 0);
            }
        if (t + 1 < ntq) KLOAD(t + 1);
        #pragma unroll
        for (int j = 0; j < 4; ++j)
            #pragma unroll
            for (int r = 0; r < 4; ++r)
                if (pos0 + 16 * j + 4 * g + r >= new_len) {
                    s[j][0][r] = -1e30f; s[j][1][r] = -1e30f;
                }
        short8 pa[2][2];
        #pragma unroll
        for (int sub = 0; sub < 2; ++sub) {
            float tm = -INFINITY;
            #pragma unroll
            for (int j = 0; j < 4; ++j)
                #pragma unroll
                for (int r = 0; r < 4; ++r) tm = fmaxf(tm, s[j][sub][r]);
            tm = fmaxf(tm, __shfl_xor(tm, 16));
            tm = fmaxf(tm, __shfl_xor(tm, 32));
            if (tm > m[sub] + 8.f) {
                const float alpha = __expf(m[sub] - tm);
                m[sub] = tm;
                l[sub] *= alpha;
                #pragma unroll
                for (int n = 0; n < 8; ++n) {
                    acc[sub][n][0] *= alpha; acc[sub][n][1] *= alpha;
                    acc[sub][n][2] *= alpha; acc[sub][n][3] *= alpha;
                }
            }
            const float mb = m[sub];
            float p[4][4];
            float rs = 0.f;
            #pragma unroll
            for (int j = 0; j < 4; ++j)
                #pragma unroll
                for (int r = 0; r < 4; ++r) {
                    p[j][r] = __expf(s[j][sub][r] - mb);
                    rs += p[j][r];
                }
            rs += __shfl_xor(rs, 16);
            rs += __shfl_xor(rs, 32);
            l[sub] += rs;
            pa[sub][0] = mkfrag(p[0], p[1]);
            pa[sub][1] = mkfrag(p[2], p[3]);
        }
        #pragma unroll
        for (int half = 0; half < 2; ++half) {
            const unsigned vb0 = (unsigned)(size_t)(smem + VBUF(b)) + half * 8448
                               + g * 256 + li * 8;
            short4v vt[16];
            #pragma unroll
            for (int h2 = 0; h2 < 8; ++h2) {
                vt[2 * h2]     = tr_read(vb0 + h2 * 1056);
                vt[2 * h2 + 1] = tr_read(vb0 + h2 * 1056 + 128);
            }
            asm volatile("s_waitcnt lgkmcnt(0)" ::: "memory");
            __builtin_amdgcn_sched_barrier(0);
            #pragma unroll
            for (int h2 = 0; h2 < 8; ++h2) {
                short8 vf = __builtin_shufflevector(vt[2 * h2], vt[2 * h2 + 1],
                                                    0, 1, 2, 3, 4, 5, 6, 7);
                acc[0][h2] = __builtin_amdgcn_mfma_f32_16x16x32_bf16(vf, pa[0][half], acc[0][h2], 0, 0, 0);
                acc[1][h2] = __builtin_amdgcn_mfma_f32_16x16x32_bf16(vf, pa[1][half], acc[1][h2], 0, 0, 0);
            }
        }
        __syncthreads();
    }

    short* op = (kvs < 2) ? (opA + (size_t)kvs * 16 * 1024 * 128)
                          : (opB + (size_t)(kvs - 2) * 16 * 1024 * 128);
    #pragma unroll
    for (int sub = 0; sub < 2; ++sub) {
        const int qrow = q0 + w * 32 + sub * 16 + li;
        const size_t ro = ((size_t)(head << 10) + qrow) * 128;
        #pragma unroll
        for (int n = 0; n < 8; ++n) {
            short4v o4;
            o4[0] = (short)f2bf(acc[sub][n][0]); o4[1] = (short)f2bf(acc[sub][n][1]);
            o4[2] = (short)f2bf(acc[sub][n][2]); o4[3] = (short)f2bf(acc[sub][n][3]);
            *(short4v*)(op + ro + 16 * n + 4 * g) = o4;
        }
        if (g == 0) {
            float* ml = mlpart + (((size_t)(kvs * 16 + head) << 10) + qrow) * 2;
            ml[0] = m[sub]; ml[1] = l[sub];
        }
    }
}

// ---------------------------------------------------------------------------
// Merge the 4 KV-split partials -> a_bf. (unchanged)
// ---------------------------------------------------------------------------
__global__ __launch_bounds__(256)
void attn_merge(const short* __restrict__ opA, const short* __restrict__ opB,
                const float* __restrict__ mlpart, short* __restrict__ a_bf) {
    int gid = blockIdx.x * 256 + threadIdx.x;
    int row = gid >> 4;
    int c8  = (gid & 15) * 8;
    int head = row >> 10, q = row & 1023;
    float mg[4], lg[4], mstar = -INFINITY;
    #pragma unroll
    for (int s = 0; s < 4; ++s) {
        const float* ml = mlpart + (((size_t)(s * 16 + head) << 10) + q) * 2;
        mg[s] = ml[0]; lg[s] = ml[1];
        mstar = fmaxf(mstar, mg[s]);
    }
    float cg[4], lstar = 0.f;
    #pragma unroll
    for (int s = 0; s < 4; ++s) { cg[s] = __expf(mg[s] - mstar); lstar += lg[s] * cg[s]; }
    const float inv = 1.0f / lstar;
    float o[8] = {};
    #pragma unroll
    for (int s = 0; s < 4; ++s) {
        const short* op = (s < 2) ? (opA + (size_t)s * 16 * 1024 * 128)
                                  : (opB + (size_t)(s - 2) * 16 * 1024 * 128);
        short8 v = *(const short8*)(op + (((size_t)(head << 10)) + q) * 128 + c8);
        #pragma unroll
        for (int j = 0; j < 8; ++j) o[j] += cg[s] * bf2f(v[j]);
    }
    short8 o8;
    #pragma unroll
    for (int j = 0; j < 8; ++j) o8[j] = (short)f2bf(o[j] * inv);
    *(short8*)(a_bf + (size_t)q * 2048 + head * 128 + c8) = o8;
}

// ---------------------------------------------------------------------------
extern "C" void kernel_launch(void* const* d_in, const int* in_sizes, int n_in,
                              void* d_out, int out_size, void* d_ws, size_t ws_size,
                              hipStream_t stream) {
    const float* x_noise       = (const float*)d_in[0];
    const float* target_hidden = (const float*)d_in[1];
    const int*   noise_pos     = (const int*)d_in[2];
    const int*   ctx_pos       = (const int*)d_in[3];
    const float* in_k          = (const float*)d_in[4];
    const float* in_v          = (const float*)d_in[5];
    const int*   clp           = (const int*)d_in[6];
    const int*   acp           = (const int*)d_in[7];
    const float* Wq            = (const float*)d_in[8];
    const float* Wk            = (const float*)d_in[9];
    const float* Wv            = (const float*)d_in[10];
    const float* Wo            = (const float*)d_in[11];
    const float* q_scale       = (const float*)d_in[12];
    const float* k_scale       = (const float*)d_in[13];

    float* out   = (float*)d_out;
    float* out_k = out + (size_t)T_NOISE * D;
    float* out_v = out_k + (size_t)NH * MAX_KV * HD;

    float* ws     = (float*)d_ws;
    const size_t M1 = 1024u * 1024u;
    short* q_tmpb = (short*)ws;                   // [0,1M) fl
    short* a_bf   = q_tmpb;                       // overlay (q dead after attn)
    short* k_tmpb = (short*)(ws + 1 * M1);        // [1M,2M)
    short* v_tmpb = (short*)(ws + 2 * M1);        // [2M,3M)
    float* mlpart = (float*)v_tmpb;               // overlay (v_tmpb dead after scatter)
    short* xbf    = (short*)(ws + 3 * M1);        // [3M,5M)
    short* opartA = xbf;                          // overlay (xbf dead after gemm_qkv)
    short* btpack = (short*)(ws + 5 * M1);        // [5M,9M)
    short* wo_t   = btpack;                       // overlay rows 0..2047 post-QKV
    short* opartB = (short*)(ws + 7 * M1);        // overlay btpack Wq rows (dead)
    short* kbf    = (short*)(ws + 9 * M1);        // [9M,13M)
    short* vbf    = (short*)(ws + 13 * M1);       // [13M,17M)

    dim3 blk(256);
    prep_all<<<4096, blk, 0, stream>>>(target_hidden, x_noise, xbf,
                                       Wk, Wv, Wq,
                                       btpack, btpack + (size_t)1024 * 2048,
                                       btpack + (size_t)2048 * 2048);
    gemm_qkv64<<<dim3(32, 32), blk, 0, stream>>>(xbf, btpack, k_tmpb, v_tmpb, q_tmpb);
    conv_transpose<<<dim3(32, 32), blk, 0, stream>>>(Wo, wo_t, 2048, 2048);
    rmsrope_wv<<<8192, blk, 0, stream>>>(q_tmpb, k_tmpb, noise_pos, ctx_pos,
                                         q_scale, k_scale);
    cache_scatter2<<<4096, blk, 0, stream>>>(in_k, in_v, k_tmpb, v_tmpb,
                                             out_k, out_v, kbf, vbf, clp, acp);
    attn_mfma<<<1024, 128, 0, stream>>>(q_tmpb, kbf, vbf, opartA, opartB, mlpart, clp, acp);
    attn_merge<<<1024, blk, 0, stream>>>(opartA, opartB, mlpart, a_bf);
    gemm_o<<<dim3(32, 16), blk, 0, stream>>>(a_bf, wo_t, out);
}